// Round 4
// baseline (42.126 us; speedup 1.0000x reference)
//
#include <hip/hip_runtime.h>
#include <math.h>

#define CLASS_P 360
#define ROW_STRIDE 4320      // C * P = 12 * 360
#define NF4 90               // float4 chunks per window (360/4)
#define RPW 2                // rows per wave
#define WPB 4                // waves per block

// One 64-lane wave handles RPW rows. Phase 1 computes three sums per row
// (S|pw|, Slw, Slw*pw) at load time -- labels are never kept in registers.
// Phase 2 computes sum(exp(pw/S|pw|)) -- safe without max-subtraction since
// |scaled| <= 1 by construction. Row loss = lse*Slw - inv*Slwpw.
// Block partials go straight to out[0] via one float atomicAdd per block
// (no threadfence -- that serialized the grid in round 2).
__global__ __launch_bounds__(256) void vp_main(
        const float* __restrict__ preds,
        const float* __restrict__ labels,
        const int*   __restrict__ cls,
        float* __restrict__ out,
        int B) {
    const int wid  = threadIdx.x >> 6;
    const int lane = threadIdx.x & 63;
    const int r0   = (blockIdx.x * WPB + wid) * RPW;
    const bool has2 = lane < (NF4 - 64);   // lane < 26

    float4 a0[RPW], a1[RPW];
    float sabs[RPW], sl[RPW], slp[RPW], wgt[RPW];

    #pragma unroll
    for (int k = 0; k < RPW; ++k) {
        const int r  = r0 + k;
        const int rr = (r < B) ? r : 0;
        wgt[k] = (r < B) ? 1.0f : 0.0f;
        const size_t base = (size_t)rr * ROW_STRIDE + (size_t)cls[rr] * CLASS_P;
        const float4* __restrict__ p4 = (const float4*)(preds + base);
        const float4* __restrict__ l4 = (const float4*)(labels + base);

        a0[k] = p4[lane];
        float4 b0 = l4[lane];
        a1[k] = make_float4(0.f, 0.f, 0.f, 0.f);
        float4 b1 = make_float4(0.f, 0.f, 0.f, 0.f);
        if (has2) { a1[k] = p4[lane + 64]; b1 = l4[lane + 64]; }

        sabs[k] = fabsf(a0[k].x) + fabsf(a0[k].y) + fabsf(a0[k].z) + fabsf(a0[k].w)
                + fabsf(a1[k].x) + fabsf(a1[k].y) + fabsf(a1[k].z) + fabsf(a1[k].w);
        sl[k]   = (b0.x + b0.y) + (b0.z + b0.w) + (b1.x + b1.y) + (b1.z + b1.w);
        slp[k]  = b0.x * a0[k].x + b0.y * a0[k].y + b0.z * a0[k].z + b0.w * a0[k].w
                + b1.x * a1[k].x + b1.y * a1[k].y + b1.z * a1[k].z + b1.w * a1[k].w;
    }

    // Merged butterfly: 3*RPW independent chains pipeline through the LDS unit.
    #pragma unroll
    for (int o = 32; o > 0; o >>= 1) {
        #pragma unroll
        for (int k = 0; k < RPW; ++k) {
            sabs[k] += __shfl_xor(sabs[k], o);
            sl[k]   += __shfl_xor(sl[k],   o);
            slp[k]  += __shfl_xor(slp[k],  o);
        }
    }

    float inv[RPW], se[RPW];
    #pragma unroll
    for (int k = 0; k < RPW; ++k) {
        inv[k] = 1.0f / sabs[k];
        float e = __expf(a0[k].x * inv[k]) + __expf(a0[k].y * inv[k])
                + __expf(a0[k].z * inv[k]) + __expf(a0[k].w * inv[k]);
        if (has2)
            e += __expf(a1[k].x * inv[k]) + __expf(a1[k].y * inv[k])
               + __expf(a1[k].z * inv[k]) + __expf(a1[k].w * inv[k]);
        se[k] = e;
    }
    #pragma unroll
    for (int o = 32; o > 0; o >>= 1) {
        #pragma unroll
        for (int k = 0; k < RPW; ++k) se[k] += __shfl_xor(se[k], o);
    }

    float acc = 0.f;
    #pragma unroll
    for (int k = 0; k < RPW; ++k) {
        const float lse = __logf(se[k]);               // logsumexp(scaled)
        acc += wgt[k] * (lse * sl[k] - inv[k] * slp[k]);
    }

    __shared__ float sm[WPB];
    if (lane == 0) sm[wid] = acc;
    __syncthreads();
    if (threadIdx.x == 0)
        atomicAdd(out, (sm[0] + sm[1]) + (sm[2] + sm[3]));
}

extern "C" void kernel_launch(void* const* d_in, const int* in_sizes, int n_in,
                              void* d_out, int out_size, void* d_ws, size_t ws_size,
                              hipStream_t stream) {
    const float* preds  = (const float*)d_in[0];
    const float* labels = (const float*)d_in[1];
    const int*   cls    = (const int*)d_in[2];
    float* out = (float*)d_out;

    const int B = in_sizes[2];                            // 16384 rows
    const int rows_per_block = WPB * RPW;                 // 8
    const int blocks = (B + rows_per_block - 1) / rows_per_block;  // 2048

    hipMemsetAsync(out, 0, sizeof(float), stream);        // capturable
    vp_main<<<blocks, 256, 0, stream>>>(preds, labels, cls, out, B);
}

// Round 5
// 19.394 us; speedup vs baseline: 2.1722x; 2.1722x over previous
//
#include <hip/hip_runtime.h>
#include <math.h>

#define CLASS_P 360
#define ROW_STRIDE 4320      // C * P = 12 * 360
#define NF4 90               // float4 chunks per window (360/4)
#define RPW 2                // rows per wave
#define WPB 4                // waves per block (256 threads)

// One 64-lane wave handles RPW rows.
// Phase 1 (at load): three sums per row -- S|pw|, Slw, S(lw*pw); labels are
// consumed immediately (never held). One merged butterfly (3*RPW chains).
// Phase 2: sum(exp(pw/S|pw|)) -- safe without max-subtraction since
// |scaled| <= 1 by construction (each |pw_j|/S|pw| <= 1). Second butterfly.
// Row loss = lse*Slw - inv*S(lw*pw); lane-uniform -> lane 0 stores the
// per-wave partial. NO atomics (rounds 2+4: same-address device atomics
// cost ~10-40ns each serialized across XCDs).
__global__ __launch_bounds__(256) void vp_main(
        const float* __restrict__ preds,
        const float* __restrict__ labels,
        const int*   __restrict__ cls,
        float* __restrict__ partial,
        int B) {
    const int wid  = threadIdx.x >> 6;
    const int lane = threadIdx.x & 63;
    const int wave = blockIdx.x * WPB + wid;
    const int r0   = wave * RPW;
    const bool has2 = lane < (NF4 - 64);   // lane < 26

    float4 a0[RPW], a1[RPW];
    float sabs[RPW], sl[RPW], slp[RPW], wgt[RPW];

    #pragma unroll
    for (int k = 0; k < RPW; ++k) {
        const int r  = r0 + k;
        const int rr = (r < B) ? r : 0;
        wgt[k] = (r < B) ? 1.0f : 0.0f;
        const size_t base = (size_t)rr * ROW_STRIDE + (size_t)cls[rr] * CLASS_P;
        const float4* __restrict__ p4 = (const float4*)(preds + base);
        const float4* __restrict__ l4 = (const float4*)(labels + base);

        a0[k] = p4[lane];
        float4 b0 = l4[lane];
        a1[k] = make_float4(0.f, 0.f, 0.f, 0.f);
        float4 b1 = make_float4(0.f, 0.f, 0.f, 0.f);
        if (has2) { a1[k] = p4[lane + 64]; b1 = l4[lane + 64]; }

        sabs[k] = fabsf(a0[k].x) + fabsf(a0[k].y) + fabsf(a0[k].z) + fabsf(a0[k].w)
                + fabsf(a1[k].x) + fabsf(a1[k].y) + fabsf(a1[k].z) + fabsf(a1[k].w);
        sl[k]   = (b0.x + b0.y) + (b0.z + b0.w) + (b1.x + b1.y) + (b1.z + b1.w);
        slp[k]  = b0.x * a0[k].x + b0.y * a0[k].y + b0.z * a0[k].z + b0.w * a0[k].w
                + b1.x * a1[k].x + b1.y * a1[k].y + b1.z * a1[k].z + b1.w * a1[k].w;
    }

    // Merged butterfly: 3*RPW independent chains pipeline through the LDS unit.
    #pragma unroll
    for (int o = 32; o > 0; o >>= 1) {
        #pragma unroll
        for (int k = 0; k < RPW; ++k) {
            sabs[k] += __shfl_xor(sabs[k], o);
            sl[k]   += __shfl_xor(sl[k],   o);
            slp[k]  += __shfl_xor(slp[k],  o);
        }
    }

    float inv[RPW], se[RPW];
    #pragma unroll
    for (int k = 0; k < RPW; ++k) {
        inv[k] = 1.0f / sabs[k];
        float e = __expf(a0[k].x * inv[k]) + __expf(a0[k].y * inv[k])
                + __expf(a0[k].z * inv[k]) + __expf(a0[k].w * inv[k]);
        if (has2)
            e += __expf(a1[k].x * inv[k]) + __expf(a1[k].y * inv[k])
               + __expf(a1[k].z * inv[k]) + __expf(a1[k].w * inv[k]);
        se[k] = e;
    }
    #pragma unroll
    for (int o = 32; o > 0; o >>= 1) {
        #pragma unroll
        for (int k = 0; k < RPW; ++k) se[k] += __shfl_xor(se[k], o);
    }

    float acc = 0.f;
    #pragma unroll
    for (int k = 0; k < RPW; ++k)
        acc += wgt[k] * (__logf(se[k]) * sl[k] - inv[k] * slp[k]);

    if (lane == 0) partial[wave] = acc;       // per-wave store, no LDS/sync
}

// Single-block deterministic reduction of n floats (n%4==0) -> out[0].
__global__ __launch_bounds__(256) void vp_reduce(
        const float* __restrict__ partial, float* __restrict__ out, int n) {
    const float4* __restrict__ p4 = (const float4*)partial;
    const int n4 = n >> 2;
    float acc = 0.f;
    for (int i = threadIdx.x; i < n4; i += 256) {
        float4 v = p4[i];
        acc += (v.x + v.y) + (v.z + v.w);
    }
    #pragma unroll
    for (int o = 32; o > 0; o >>= 1) acc += __shfl_xor(acc, o);

    __shared__ float sm[4];
    const int wid = threadIdx.x >> 6, lane = threadIdx.x & 63;
    if (lane == 0) sm[wid] = acc;
    __syncthreads();
    if (threadIdx.x == 0) out[0] = (sm[0] + sm[1]) + (sm[2] + sm[3]);
}

extern "C" void kernel_launch(void* const* d_in, const int* in_sizes, int n_in,
                              void* d_out, int out_size, void* d_ws, size_t ws_size,
                              hipStream_t stream) {
    const float* preds  = (const float*)d_in[0];
    const float* labels = (const float*)d_in[1];
    const int*   cls    = (const int*)d_in[2];
    float* out = (float*)d_out;
    float* ws  = (float*)d_ws;

    const int B = in_sizes[2];                       // 16384 rows
    const int waves  = (B + RPW - 1) / RPW;          // 8192
    const int blocks = (waves + WPB - 1) / WPB;      // 2048

    vp_main<<<blocks, 256, 0, stream>>>(preds, labels, cls, ws, B);
    vp_reduce<<<1, 256, 0, stream>>>(ws, out, waves);
}